// Round 1
// baseline (2024.274 us; speedup 1.0000x reference)
//
#include <hip/hip_runtime.h>

#define NB 8192
#define NH 128
#define NLB 64
#define NPW 32
#define NWL 96

// ---------------- Kernel A: covariance / gain recursion ----------------
// One launch per filter step t = 0..64.  Grid: 64 WGs x 256 threads.
// Launch t:
//   Psrc = (t==0) ? init_cov : Pbuf[(t-1)&1]
//   if t>0: v = Psrc*h_{t-1}, w = Psrc^T*h_{t-1}, s = h.v + R,
//           ktab[t-1] = v/s   (downdate applied analytically below)
//   if t<64: Pbuf[t&1] = F_t (Psrc - v w^T/s) F_t^T + Q
__global__ __launch_bounds__(256)
void cov_step(const float* __restrict__ Fw,
              const float* __restrict__ Hw,
              const float* __restrict__ Qm,
              const float* __restrict__ Rm,
              const float* __restrict__ init_cov,
              float* __restrict__ Pbuf,
              float* __restrict__ ktab,
              int t)
{
    const int tid = threadIdx.x;
    __shared__ float hh[NH], vv[NH], ww[NH];
    __shared__ float tmp[2 * 132];
    __shared__ float fvs[2];
    __shared__ float s_inv_sh;

    const float* Psrc = (t == 0) ? init_cov : (Pbuf + ((t - 1) & 1) * (NH * NH));
    const float* Frow = Fw + (size_t)t * NH * NH;  // only dereferenced when t<64

    if (tid < NH) hh[tid] = (t > 0) ? Hw[(t - 1) * NH + tid] : 0.0f;
    __syncthreads();

    if (t > 0) {
        if (tid < NH) {                       // v = P h  (row dots)
            float acc = 0.0f;
            const float* pr = Psrc + tid * NH;
            for (int j = 0; j < NH; ++j) acc += pr[j] * hh[j];
            vv[tid] = acc;
        } else {                              // w = P^T h (col dots)
            const int j = tid - NH;
            float acc = 0.0f;
            for (int i = 0; i < NH; ++i) acc += hh[i] * Psrc[i * NH + j];
            ww[j] = acc;
        }
    } else {
        if (tid < NH) { vv[tid] = 0.0f; ww[tid] = 0.0f; }
    }
    __syncthreads();

    if (tid == 0) {
        if (t > 0) {
            float s = Rm[0];
            for (int i = 0; i < NH; ++i) s += hh[i] * vv[i];
            s_inv_sh = 1.0f / s;
        } else {
            s_inv_sh = 0.0f;                  // downdate term vanishes at t==0
        }
    }
    __syncthreads();
    const float s_inv = s_inv_sh;

    if (t > 0 && blockIdx.x == 0 && tid < NH)
        ktab[(t - 1) * NH + tid] = vv[tid] * s_inv;
    if (t == NLB) return;                     // launch 64 only produces ktab[63]

    const int I0 = blockIdx.x * 2;            // this WG's two output rows

    if (tid < 2) {                            // fv[i] = F[I0+i,:] . v
        float acc = 0.0f;
        const float* fr = Frow + (I0 + tid) * NH;
        for (int m = 0; m < NH; ++m) acc += fr[m] * vv[m];
        fvs[tid] = acc;
    }
    __syncthreads();

    {   // phase A: tmp[i][k] = F[I0+i,:] . P_eff[:,k]
        const int i = tid >> 7;               // 0..1
        const int k = tid & 127;
        const float* fr = Frow + (I0 + i) * NH;
        float acc = 0.0f;
        for (int m = 0; m < NH; ++m) acc += fr[m] * Psrc[m * NH + k];
        tmp[i * 132 + k] = acc - fvs[i] * ww[k] * s_inv;
    }
    __syncthreads();

    {   // phase B: Pdst[I0+i][j] = tmp[i,:] . F[j,:] + Q[I0+i][j]
        const int i = tid >> 7;
        const int j = tid & 127;
        const float* tr = &tmp[i * 132];
        const float* fj = Frow + j * NH;
        float acc = 0.0f;
        for (int k = 0; k < NH; ++k) acc += tr[k] * fj[k];
        float* Pdst = Pbuf + (t & 1) * (NH * NH);
        Pdst[(I0 + i) * NH + j] = acc + Qm[(I0 + i) * NH + j];
    }
}

// ---------------- Kernel B: batched state filter + prediction ----------------
// Grid: 256 WGs x 256 threads.  Each WG owns 32 batch rows; hs tile lives in
// LDS across all 96 steps.  Weights staged per step in two k-halves.
// Per-thread 4x4 tile: rows r0..r0+3 (contiguous), cols {cq, cq+32, cq+64, cq+96}
// so LDS b-operand lane stride is 68 floats (== 4 mod 32): conflict-free.
__global__ __launch_bounds__(256)
void batch_filter(const float* __restrict__ x,
                  const float* __restrict__ Fw,
                  const float* __restrict__ Fb,
                  const float* __restrict__ Hw,
                  const float* __restrict__ Hb,
                  const float* __restrict__ init_state,
                  const float* __restrict__ ktab,
                  float* __restrict__ out)
{
    const int tid = threadIdx.x;
    const int b0  = blockIdx.x * 32;

    __shared__ float hs[32 * 132];        // state tile, padded stride 132
    __shared__ float Wl[128 * 68];        // half-K weight tile, padded stride 68
    __shared__ float hl[NH], kl[NH], fbl[NH];
    __shared__ float resid[32];

    // init hs: every row = init_state
    for (int e = 0; e < 16; ++e) {
        const int idx = e * 256 + tid;    // 0..4095
        const int r = idx >> 7, c = idx & 127;
        hs[r * 132 + c] = init_state[c];
    }

    const int r0 = (tid >> 5) << 2;       // 0,4,...,28
    const int cq = tid & 31;              // column base within quarter

    for (int t = 0; t < NWL; ++t) {
        const float* Wt = Fw + (size_t)t * NH * NH;
        if (tid < NH) {
            hl[tid]  = Hw[t * NH + tid];
            fbl[tid] = Fb[t * NH + tid];
            if (t < NLB) kl[tid] = ktab[t * NH + tid];
        }
        __syncthreads();                  // covers hs init on t==0 too

        float acc[4][4];
#pragma unroll
        for (int i = 0; i < 4; ++i)
#pragma unroll
            for (int j = 0; j < 4; ++j) acc[i][j] = fbl[cq + 32 * j];

        for (int kp = 0; kp < 2; ++kp) {
            // stage Wl[c][0..63] = Fw_t[c][kp*64 .. kp*64+63]
#pragma unroll
            for (int e = 0; e < 8; ++e) {
                const int f4 = e * 256 + tid;          // 0..2047
                const int c = f4 >> 4, k4 = (f4 & 15) << 2;
                *(float4*)&Wl[c * 68 + k4] =
                    *(const float4*)&Wt[c * NH + kp * 64 + k4];
            }
            __syncthreads();

#pragma unroll
            for (int k4 = 0; k4 < 64; k4 += 4) {
                float4 a[4], bb[4];
#pragma unroll
                for (int i = 0; i < 4; ++i)
                    a[i] = *(const float4*)&hs[(r0 + i) * 132 + kp * 64 + k4];
#pragma unroll
                for (int j = 0; j < 4; ++j)
                    bb[j] = *(const float4*)&Wl[(cq + 32 * j) * 68 + k4];
#pragma unroll
                for (int i = 0; i < 4; ++i)
#pragma unroll
                    for (int j = 0; j < 4; ++j)
                        acc[i][j] += a[i].x * bb[j].x + a[i].y * bb[j].y
                                   + a[i].z * bb[j].z + a[i].w * bb[j].w;
            }
            __syncthreads();              // before restaging Wl / writing hs
        }

        // write back hs_pred
#pragma unroll
        for (int i = 0; i < 4; ++i)
#pragma unroll
            for (int j = 0; j < 4; ++j)
                hs[(r0 + i) * 132 + cq + 32 * j] = acc[i][j];
        __syncthreads();

        if (t < NLB) {
            // residual and Kalman correction
            if (tid < 32) {
                float yp = 0.0f;
                const float* row = &hs[tid * 132];
                for (int c = 0; c < NH; ++c) yp += row[c] * hl[c];
                resid[tid] = x[(b0 + tid) * NLB + t] - yp;
            }
            __syncthreads();
#pragma unroll
            for (int e = 0; e < 16; ++e) {
                const int idx = e * 256 + tid;
                const int r = idx >> 7, c = idx & 127;
                hs[r * 132 + c] += kl[c] * resid[r];
            }
            __syncthreads();
        } else {
            // emission
            if (tid < 32) {
                float em = Hb[t];
                const float* row = &hs[tid * 132];
                for (int c = 0; c < NH; ++c) em += row[c] * hl[c];
                out[(b0 + tid) * NPW + (t - NLB)] = em;
            }
            __syncthreads();              // protect hl before next-step staging
        }
    }
}

extern "C" void kernel_launch(void* const* d_in, const int* in_sizes, int n_in,
                              void* d_out, int out_size, void* d_ws, size_t ws_size,
                              hipStream_t stream) {
    const float* x          = (const float*)d_in[0];
    const float* F_w        = (const float*)d_in[1];
    const float* F_b        = (const float*)d_in[2];
    const float* H_w        = (const float*)d_in[3];
    const float* H_b        = (const float*)d_in[4];
    const float* init_state = (const float*)d_in[5];
    const float* init_cov   = (const float*)d_in[6];
    const float* Qm         = (const float*)d_in[7];
    const float* Rm         = (const float*)d_in[8];
    float* outp = (float*)d_out;

    float* Pbuf = (float*)d_ws;              // 2 * 128*128 floats (128 KB)
    float* ktab = Pbuf + 2 * NH * NH;        // 64 * 128 floats   (32 KB)

    for (int t = 0; t <= NLB; ++t)
        cov_step<<<dim3(64), dim3(256), 0, stream>>>(F_w, H_w, Qm, Rm, init_cov,
                                                     Pbuf, ktab, t);

    batch_filter<<<dim3(NB / 32), dim3(256), 0, stream>>>(
        x, F_w, F_b, H_w, H_b, init_state, ktab, outp);
}

// Round 2
// 1796.411 us; speedup vs baseline: 1.1268x; 1.1268x over previous
//
#include <hip/hip_runtime.h>

#define NB 8192
#define NH 128
#define NLB 64
#define NPW 32
#define NWL 96
#define NWG 32

// ---- device-scope epoch barrier (ws-backed; works with 0x00 or 0xAA init:
// both give slot values < 1 as signed int, and epochs count 1,2,3,...) ----
__device__ __forceinline__ void gbar(int* bar, int wg, int tid, int epoch) {
    __syncthreads();                       // drains vmcnt (all WG writes in L2)
    if (tid == 0) {
        __threadfence();                   // device-scope release (L2 wb)
        __atomic_store_n(&bar[wg * 16], epoch, __ATOMIC_RELEASE);
    }
    if (tid < NWG) {
        while (__atomic_load_n(&bar[tid * 16], __ATOMIC_ACQUIRE) < epoch) {}
    }
    __syncthreads();
    __threadfence();                       // reader-side invalidate
}

__global__ __launch_bounds__(256)
void kalman_fused(const float* __restrict__ x,
                  const float* __restrict__ Fw,
                  const float* __restrict__ Fb,
                  const float* __restrict__ Hw,
                  const float* __restrict__ Hb,
                  const float* __restrict__ init_state,
                  const float* __restrict__ init_cov,
                  const float* __restrict__ Qm,
                  const float* __restrict__ Rm,
                  float* __restrict__ ws,
                  float* __restrict__ out)
{
    const int tid = threadIdx.x;
    const int wg  = blockIdx.x;

    int*   bar  = (int*)ws;                  // 32 slots, stride 16 ints (2 KB)
    float* PPb0 = ws + 512;
    float* PPb1 = PPb0 + NH * NH;
    float* Gb0  = PPb1 + NH * NH;
    float* Gb1  = Gb0 + NH * 64;
    float* gb0  = Gb1 + NH * 64;
    float* gb1  = gb0 + NH;
    float* Mrow = gb1 + NH;                  // 32*64
    float* dvec = Mrow + NPW * 64;           // 32

    float* PPb[2] = { PPb0, PPb1 };
    float* Gb[2]  = { Gb0,  Gb1  };
    float* gb[2]  = { gb0,  gb1  };

    __shared__ float sh_h[NH], sh_v[NH], sh_w[NH], sh_k[NH], sh_z[NH], sh_g[NH];
    __shared__ float sh_r[64];
    __shared__ float sh_tmp[4 * NH];
    __shared__ float sh_scal[4];

    // init affine map: G = 0, g = init_state  (rows wg*4..wg*4+3)
    for (int rr = 0; rr < 4; ++rr) {
        int r = wg * 4 + rr;
        if (tid < 64) Gb[0][r * 64 + tid] = 0.0f;
    }
    if (tid < 4) gb[0][wg * 4 + tid] = init_state[wg * 4 + tid];

    const float Rv = Rm[0];

    // ---- 65 barrier-separated iterations: cov recursion + G/g propagation ----
    for (int tau = 0; tau <= NLB; ++tau) {
        const float* PPcur = PPb[(tau + 1) & 1];   // P_pred_{tau-1}
        float*       PPnxt = PPb[tau & 1];
        const float* Gcur  = Gb[(tau + 1) & 1];    // G after filter step tau-2
        float*       Gnxt  = Gb[tau & 1];
        const float* gcur  = gb[(tau + 1) & 1];
        float*       gnxt  = gb[tau & 1];

        if (tau >= 1) {
            if (tid < NH) { sh_h[tid] = Hw[(tau - 1) * NH + tid]; sh_g[tid] = gcur[tid]; }
        } else {
            if (tid < NH) { sh_v[tid] = 0.0f; sh_w[tid] = 0.0f; }
        }
        __syncthreads();

        float s_inv = 0.0f;
        if (tau >= 1) {
            // (a) redundant per WG: v = PP h, w = PP^T h, s, k_{tau-1}
            if (tid < NH) {
                float acc = 0.0f;
                for (int i = 0; i < NH; ++i) acc += sh_h[i] * PPcur[i * NH + tid];
                sh_w[tid] = acc;
            } else {
                const int m = tid - NH;
                const float* row = PPcur + m * NH;
                float acc = 0.0f;
                for (int j = 0; j < NH; j += 4) {
                    float4 p = *(const float4*)&row[j];
                    acc += p.x * sh_h[j] + p.y * sh_h[j + 1]
                         + p.z * sh_h[j + 2] + p.w * sh_h[j + 3];
                }
                sh_v[m] = acc;
            }
            __syncthreads();
            float s = Rv;
            for (int i = 0; i < NH; ++i) s += sh_h[i] * sh_v[i];
            s_inv = 1.0f / s;
            if (tid < NH) sh_k[tid] = sh_v[tid] * s_inv;   // consumed after later syncs
        }

        if (tau <= NLB - 1) {
            // (b) P_pred_tau rows = F_tau (PP - v w^T/s) F_tau^T + Q   (row-local)
            const float* F    = Fw + (size_t)tau * NH * NH;
            const float* Psrc = (tau == 0) ? init_cov : PPcur;
            {
                const int rloc = tid >> 6;
                const int r    = wg * 4 + rloc;
                const int lane = tid & 63;
                const float* Frow = F + r * NH;
                float a0 = 0.0f, a1 = 0.0f, fv = 0.0f;
                for (int m = 0; m < NH; ++m) {
                    float f = Frow[m];
                    a0 += f * Psrc[m * NH + lane];
                    a1 += f * Psrc[m * NH + lane + 64];
                    fv += f * sh_v[m];
                }
                sh_tmp[rloc * NH + lane]      = a0 - fv * sh_w[lane] * s_inv;
                sh_tmp[rloc * NH + lane + 64] = a1 - fv * sh_w[lane + 64] * s_inv;
            }
            __syncthreads();
            {
                const int j  = tid & 127;
                const int rp = tid >> 7;
                const float* Fj = F + j * NH;
                const float* t0 = sh_tmp + (2 * rp) * NH;
                const float* t1 = t0 + NH;
                float b0 = 0.0f, b1 = 0.0f;
                for (int k = 0; k < NH; k += 4) {
                    float4 f4 = *(const float4*)&Fj[k];
                    b0 += f4.x * t0[k] + f4.y * t0[k + 1] + f4.z * t0[k + 2] + f4.w * t0[k + 3];
                    b1 += f4.x * t1[k] + f4.y * t1[k + 1] + f4.z * t1[k + 2] + f4.w * t1[k + 3];
                }
                const int r0g = wg * 4 + 2 * rp;
                PPnxt[(size_t)r0g * NH + j]       = b0 + Qm[r0g * NH + j];
                PPnxt[(size_t)(r0g + 1) * NH + j] = b1 + Qm[(r0g + 1) * NH + j];
            }
        }
        __syncthreads();

        if (tau >= 1) {
            // (c) G/g update for filter step tau-1 (uses F_{tau-1}, k_{tau-1})
            const float* Fp  = Fw + (size_t)(tau - 1) * NH * NH;
            const float* fbp = Fb + (tau - 1) * NH;
            if (tid < NH) {
                float acc = 0.0f;
                for (int i = 0; i < NH; ++i) acc += sh_h[i] * Fp[i * NH + tid];
                sh_z[tid] = acc;                      // z = F^T h
            }
            __syncthreads();
            if (tid < 64) {
                float acc = 0.0f;
                for (int m = 0; m < NH; ++m) acc += sh_z[m] * Gcur[m * 64 + tid];
                sh_r[tid] = acc;                      // r = z G
            } else if (tid == 64) {
                float acc = 0.0f;
                for (int m = 0; m < NH; ++m) acc += sh_z[m] * sh_g[m];
                sh_scal[2] = acc;                     // z·g
            } else if (tid == 65) {
                float hfb = 0.0f;
                for (int i = 0; i < NH; ++i) hfb += sh_h[i] * fbp[i];
                sh_scal[3] = hfb + Hb[tau - 1];       // h·fb + hb
            }
            __syncthreads();
            {
                const int rloc = tid >> 6;
                const int r    = wg * 4 + rloc;
                const int c    = tid & 63;
                const float* Fr = Fp + r * NH;
                float acc = 0.0f, gacc = 0.0f;
                for (int m = 0; m < NH; ++m) {
                    float f = Fr[m];
                    acc  += f * Gcur[m * 64 + c];
                    gacc += f * sh_g[m];
                }
                const float kr  = sh_k[r];
                const float eps = -(sh_scal[2] + sh_scal[3]);
                const float e   = ((c == tau - 1) ? 1.0f : 0.0f) - sh_r[c];
                Gnxt[r * 64 + c] = acc + kr * e;
                if (c == 0) gnxt[r] = gacc + fbp[r] + kr * eps;
            }
        }

        gbar(bar, wg, tid, tau + 1);
    }

    // ---- prediction chains: WG w owns step pt = 64+w; zero barriers ----
    {
        const float* Gf = Gb[0];
        const float* gf = gb[0];
        const int pt = NLB + wg;
        if (tid < NH) sh_z[tid] = Hw[pt * NH + tid];    // u = h_pt
        if (tid == 0) sh_scal[2] = Hb[pt];              // running d
        __syncthreads();
        for (int j = pt; j >= NLB; --j) {
            const float* Fj  = Fw + (size_t)j * NH * NH;
            const float* fbj = Fb + j * NH;
            if (tid < NH) {
                float acc = 0.0f;
                for (int i = 0; i < NH; ++i) acc += sh_z[i] * Fj[i * NH + tid];
                sh_v[tid] = acc;                        // u_new = F_j^T u
                sh_w[tid] = sh_z[tid] * fbj[tid];       // for d += u·fb_j
            }
            __syncthreads();
            if (tid < 32) sh_w[tid] += sh_w[tid + 32] + sh_w[tid + 64] + sh_w[tid + 96];
            __syncthreads();
            if (tid == 0) {
                float a = 0.0f;
                for (int i = 0; i < 32; ++i) a += sh_w[i];
                sh_scal[2] += a;
            }
            if (tid < NH) sh_z[tid] = sh_v[tid];
            __syncthreads();
        }
        if (tid < 64) {
            float acc = 0.0f;
            for (int m = 0; m < NH; ++m) acc += sh_z[m] * Gf[m * 64 + tid];
            Mrow[wg * 64 + tid] = acc;
        } else if (tid == 64) {
            float acc = 0.0f;
            for (int m = 0; m < NH; ++m) acc += sh_z[m] * gf[m];
            dvec[wg] = sh_scal[2] + acc;
        }
    }
    gbar(bar, wg, tid, NLB + 2);

    // ---- batch pass: out[b,:] = M x[b,:] + d  (8192x64 @ 64x32) ----
    {
        __shared__ float Ml[NPW * 65];    // pad 65: quad-lane stride 8*65 = 8 mod 32
        __shared__ float dl[NPW];
        __shared__ float xs[64 * 68];     // pad 68: 16B-aligned, 2-way-free banks
        for (int idx = tid; idx < NPW * 64; idx += 256) {
            int p = idx >> 6, t = idx & 63;
            Ml[p * 65 + t] = Mrow[p * 64 + t];
        }
        if (tid < NPW) dl[tid] = dvec[tid];
        __syncthreads();

        const int base_b = wg * 256;
        for (int chunk = 0; chunk < 4; ++chunk) {
            const int b0 = base_b + chunk * 64;
            for (int q = 0; q < 4; ++q) {
                int f4 = q * 256 + tid;                 // 0..1023
                int rr = f4 >> 4, c4 = (f4 & 15) << 2;
                *(float4*)&xs[rr * 68 + c4] =
                    *(const float4*)&x[(size_t)(b0 + rr) * NLB + c4];
            }
            __syncthreads();
            const int rr = tid >> 2;                    // 0..63
            const int pg = tid & 3;
            const float* xr = &xs[rr * 68];
            float acc[8];
#pragma unroll
            for (int pi = 0; pi < 8; ++pi) acc[pi] = dl[pg * 8 + pi];
            for (int t = 0; t < NLB; ++t) {
                float xv = xr[t];
#pragma unroll
                for (int pi = 0; pi < 8; ++pi)
                    acc[pi] += xv * Ml[(pg * 8 + pi) * 65 + t];
            }
            float* op = out + (size_t)(b0 + rr) * NPW + pg * 8;
            *(float4*)op       = make_float4(acc[0], acc[1], acc[2], acc[3]);
            *(float4*)(op + 4) = make_float4(acc[4], acc[5], acc[6], acc[7]);
            __syncthreads();
        }
    }
}

extern "C" void kernel_launch(void* const* d_in, const int* in_sizes, int n_in,
                              void* d_out, int out_size, void* d_ws, size_t ws_size,
                              hipStream_t stream) {
    const float* x          = (const float*)d_in[0];
    const float* F_w        = (const float*)d_in[1];
    const float* F_b        = (const float*)d_in[2];
    const float* H_w        = (const float*)d_in[3];
    const float* H_b        = (const float*)d_in[4];
    const float* init_state = (const float*)d_in[5];
    const float* init_cov   = (const float*)d_in[6];
    const float* Qm         = (const float*)d_in[7];
    const float* Rm         = (const float*)d_in[8];

    kalman_fused<<<dim3(NWG), dim3(256), 0, stream>>>(
        x, F_w, F_b, H_w, H_b, init_state, init_cov, Qm, Rm,
        (float*)d_ws, (float*)d_out);
}

// Round 3
// 1647.804 us; speedup vs baseline: 1.2285x; 1.0902x over previous
//
#include <hip/hip_runtime.h>

#define NB 8192
#define NH 128
#define NLB 64
#define NPW 32
#define NWG 32
#define NT 1024

// ---- device-scope epoch barrier (ws-backed; 0xAA poison reads as negative
// int so epochs 1,2,3,... always advance past it) ----
__device__ __forceinline__ void gbar(int* bar, int wg, int tid, int epoch) {
    __syncthreads();                       // compiler drains vmcnt before s_barrier
    if (tid == 0) {
        __threadfence();                   // device-scope release
        __atomic_store_n(&bar[wg * 16], epoch, __ATOMIC_RELEASE);
    }
    if (tid < NWG) {
        while (__atomic_load_n(&bar[tid * 16], __ATOMIC_ACQUIRE) < epoch) {
            __builtin_amdgcn_s_sleep(1);
        }
    }
    __syncthreads();
    __threadfence();                       // reader-side invalidate
}

__device__ __forceinline__ float wave_reduce(float a) {
#pragma unroll
    for (int off = 32; off; off >>= 1) a += __shfl_down(a, off);
    return a;
}

__global__ __launch_bounds__(1024)
void kalman_fused(const float* __restrict__ x,
                  const float* __restrict__ Fw,
                  const float* __restrict__ Fb,
                  const float* __restrict__ Hw,
                  const float* __restrict__ Hb,
                  const float* __restrict__ init_state,
                  const float* __restrict__ init_cov,
                  const float* __restrict__ Qm,
                  const float* __restrict__ Rm,
                  float* __restrict__ ws,
                  float* __restrict__ out)
{
    const int tid = threadIdx.x;
    const int wg  = blockIdx.x;

    int*   bar  = (int*)ws;                  // 32 slots, stride 16 ints
    float* PPb0 = ws + 512;
    float* PPb1 = PPb0 + NH * NH;
    float* Gb0  = PPb1 + NH * NH;
    float* Gb1  = Gb0 + NH * 64;
    float* gb0  = Gb1 + NH * 64;
    float* gb1  = gb0 + NH;
    float* Mrow = gb1 + NH;                  // 32*64
    float* dvec = Mrow + NPW * 64;           // 32

    float* PPb[2] = { PPb0, PPb1 };
    float* Gb[2]  = { Gb0,  Gb1  };
    float* gb[2]  = { gb0,  gb1  };

    __shared__ float sbuf[8704];             // F k-half tile (stride 65) / x tile (stride 68)
    __shared__ float sh_part[1024];
    __shared__ float sh_tmp[512];            // T rows (4x128) / fg partials
    __shared__ float sh_h[NH], sh_v[NH], sh_w[NH], sh_k[NH], sh_z[NH], sh_g[NH];
    __shared__ float sh_r[64];
    __shared__ float sh_fv[4];
    __shared__ float sh_scal[4];
    __shared__ float Ml[NPW * 65];
    __shared__ float dl[NPW];

    const int r_wg = wg * 4;

    // init affine map: G = 0 (this WG's 4 rows), g = init_state
    if (tid < 256) Gb[0][(r_wg + (tid >> 6)) * 64 + (tid & 63)] = 0.0f;
    if (tid < 4)   gb[0][r_wg + tid] = init_state[r_wg + tid];
    const float Rv = Rm[0];

    for (int tau = 0; tau <= NLB; ++tau) {
        const float* PPcur = PPb[(tau + 1) & 1];
        float*       PPnxt = PPb[tau & 1];
        const float* Gcur  = Gb[(tau + 1) & 1];
        float*       Gnxt  = Gb[tau & 1];
        const float* gcur  = gb[(tau + 1) & 1];
        float*       gnxt  = gb[tau & 1];
        const float* F     = Fw + (size_t)tau * NH * NH;         // tau < 64 only
        const float* Fp    = Fw + (size_t)(tau - 1) * NH * NH;   // tau >= 1 only
        const float* fbp   = Fb + (tau - 1) * NH;

        if (tau >= 1) {
            if (tid < NH) { sh_h[tid] = Hw[(tau - 1) * NH + tid]; sh_g[tid] = gcur[tid]; }
        } else {
            if (tid < NH) { sh_v[tid] = 0.0f; sh_w[tid] = 0.0f; }
            if (tid == 0) sh_scal[0] = 0.0f;
            if (tid < 4)  sh_fv[tid] = 0.0f;
        }
        __syncthreads();                                          // S1

        if (tau >= 1) {
            // ---- v = PP h (rows), w = PP^T h (cols), split partials ----
            if (tid < 512) {
                const int i = tid >> 2, o = tid & 3;
                const float* row = PPcur + (size_t)i * NH + o * 32;
                const float* hh  = sh_h + o * 32;
                float a = 0.0f;
#pragma unroll
                for (int k = 0; k < 32; k += 4) {
                    float4 p = *(const float4*)&row[k];
                    a += p.x * hh[k] + p.y * hh[k + 1] + p.z * hh[k + 2] + p.w * hh[k + 3];
                }
                sh_part[tid] = a;
            } else {
                const int t2 = tid - 512;
                const int c = t2 & 127, ib = t2 >> 7;             // ib 0..3
                const float* base = PPcur + (size_t)(ib * 32) * NH + c;
                float a = 0.0f;
#pragma unroll 8
                for (int i = 0; i < 32; ++i) a += sh_h[ib * 32 + i] * base[(size_t)i * NH];
                sh_part[tid] = a;
            }
            __syncthreads();                                      // S2
            if (tid < NH) {
                sh_v[tid] = sh_part[tid * 4] + sh_part[tid * 4 + 1]
                          + sh_part[tid * 4 + 2] + sh_part[tid * 4 + 3];
            } else if (tid < 256) {
                const int c = tid - NH;
                sh_w[c] = sh_part[512 + c] + sh_part[640 + c]
                        + sh_part[768 + c] + sh_part[896 + c];
            }
            __syncthreads();                                      // S3
            // ---- s reduce (wave 0) + fv partials (threads 64..95) ----
            if (tid < 64) {
                float a = sh_h[tid] * sh_v[tid] + sh_h[tid + 64] * sh_v[tid + 64];
                a = wave_reduce(a);
                if (tid == 0) sh_scal[0] = 1.0f / (Rv + a);
            } else if (tid < 96 && tau < NLB) {
                const int rl = (tid - 64) >> 3, o = tid & 7;
                const float* fr = F + (size_t)(r_wg + rl) * NH + o * 16;
                const float* vv = sh_v + o * 16;
                float a = 0.0f;
#pragma unroll
                for (int k = 0; k < 16; ++k) a += fr[k] * vv[k];
                sh_part[tid] = a;
            }
            __syncthreads();                                      // S4
            if (tid < NH) sh_k[tid] = sh_v[tid] * sh_scal[0];
            if (tid < 4 && tau < NLB) {
                float a = 0.0f;
#pragma unroll
                for (int o = 0; o < 8; ++o) a += sh_part[64 + tid * 8 + o];
                sh_fv[tid] = a;
            }
            __syncthreads();                                      // S5
        }

        if (tau < NLB) {
            // ---- part1: T = F (P_eff) rows, downdate folded ----
            {
                const int hm = tid >> 9, rl = (tid >> 7) & 3, c = tid & 127;
                const float* fr = F + (size_t)(r_wg + rl) * NH + hm * 64;
                const float* Psrc0 = (tau == 0) ? init_cov : PPcur;
                const float* pc = Psrc0 + (size_t)(hm * 64) * NH + c;
                float a = 0.0f;
#pragma unroll 8
                for (int m = 0; m < 64; ++m) a += fr[m] * pc[(size_t)m * NH];
                sh_part[tid] = a;
            }
            __syncthreads();                                      // S6
            if (tid < 512) {
                const int rl = tid >> 7, c = tid & 127;
                sh_tmp[tid] = sh_part[tid] + sh_part[tid + 512]
                            - sh_fv[rl] * sh_w[c] * sh_scal[0];
            }
            __syncthreads();                                      // S7
            // ---- part2: P' = T F^T + Q, F staged in LDS (stride 65) ----
            float acc2 = 0.0f;
            const int hk = tid >> 9, rl2 = (tid >> 7) & 3, j = tid & 127;
            for (int kh = 0; kh < 2; ++kh) {
                {
                    const int jj = tid >> 3, q = tid & 7;
                    const float* src = F + (size_t)jj * NH + kh * 64 + q * 8;
                    float4 p0 = *(const float4*)src;
                    float4 p1 = *(const float4*)(src + 4);
                    float* dst = sbuf + jj * 65 + q * 8;
                    dst[0] = p0.x; dst[1] = p0.y; dst[2] = p0.z; dst[3] = p0.w;
                    dst[4] = p1.x; dst[5] = p1.y; dst[6] = p1.z; dst[7] = p1.w;
                }
                __syncthreads();                                  // stage ready
                {
                    const float* tr = sh_tmp + rl2 * NH + kh * 64 + hk * 32;
                    const float* fj = sbuf + j * 65 + hk * 32;
                    float a = 0.0f;
#pragma unroll 8
                    for (int kk = 0; kk < 32; ++kk) a += tr[kk] * fj[kk];
                    acc2 += a;
                }
                __syncthreads();                                  // before restage
            }
            sh_part[tid] = acc2;
            __syncthreads();                                      // S12
            if (tid < 512) {
                const int rl = tid >> 7, j2 = tid & 127;
                const int rg = r_wg + rl;
                PPnxt[(size_t)rg * NH + j2] = sh_part[tid] + sh_part[tid + 512]
                                            + Qm[(size_t)rg * NH + j2];
            }
        }
        __syncthreads();                                          // protect sh_part

        if (tau >= 1) {
            // ---- phase c: G/g update for filter step tau-1 ----
            {
                const int ib = tid >> 7, c = tid & 127;
                const float* base = Fp + (size_t)(ib * 16) * NH + c;
                float a = 0.0f;
#pragma unroll 8
                for (int i = 0; i < 16; ++i) a += sh_h[ib * 16 + i] * base[(size_t)i * NH];
                sh_part[tid] = a;
            }
            __syncthreads();                                      // S13
            if (tid < NH) {
                float a = 0.0f;
#pragma unroll
                for (int ib = 0; ib < 8; ++ib) a += sh_part[ib * NH + tid];
                sh_z[tid] = a;                                    // z = F^T h
            }
            __syncthreads();                                      // S14
            {
                const int mb = tid >> 6, c2 = tid & 63;
                const float* base = Gcur + (size_t)(mb * 8) * 64 + c2;
                float a = 0.0f;
#pragma unroll
                for (int m = 0; m < 8; ++m) a += sh_z[mb * 8 + m] * base[(size_t)m * 64];
                sh_part[tid] = a;
            }
            __syncthreads();                                      // S15
            if (tid < 64) {
                float a = 0.0f;
#pragma unroll
                for (int mb = 0; mb < 16; ++mb) a += sh_part[mb * 64 + tid];
                sh_r[tid] = a;                                    // r = z G
            } else if (tid < 128) {
                const int l = tid - 64;
                float a = sh_z[l] * sh_g[l] + sh_z[l + 64] * sh_g[l + 64];
                a = wave_reduce(a);
                if (l == 0) sh_scal[2] = a;                       // z.g
            } else if (tid < 192) {
                const int l = tid - 128;
                float a = sh_h[l] * fbp[l] + sh_h[l + 64] * fbp[l + 64];
                a = wave_reduce(a);
                if (l == 0) sh_scal[3] = a + Hb[tau - 1];         // h.fb + hb
            }
            __syncthreads();                                      // S16
            {
                const int qm = tid >> 8, rl = (tid >> 6) & 3, c2 = tid & 63;
                const float* fr = Fp + (size_t)(r_wg + rl) * NH + qm * 32;
                const float* gc = Gcur + (size_t)(qm * 32) * 64 + c2;
                float a = 0.0f;
#pragma unroll 8
                for (int m = 0; m < 32; ++m) a += fr[m] * gc[(size_t)m * 64];
                sh_part[tid] = a;
            }
            __syncthreads();                                      // S17
            if (tid < 256) {
                const int rl = tid >> 6, c2 = tid & 63;
                const int rg = r_wg + rl;
                float val = sh_part[tid] + sh_part[tid + 256]
                          + sh_part[tid + 512] + sh_part[tid + 768];
                float e = ((c2 == tau - 1) ? 1.0f : 0.0f) - sh_r[c2];
                Gnxt[(size_t)rg * 64 + c2] = val + sh_k[rg] * e;
            } else if (tid < 288) {
                const int rl = (tid - 256) >> 3, o = tid & 7;
                const float* fr = Fp + (size_t)(r_wg + rl) * NH + o * 16;
                float a = 0.0f;
#pragma unroll
                for (int m = 0; m < 16; ++m) a += fr[m] * sh_g[o * 16 + m];
                sh_tmp[tid - 256] = a;
            }
            __syncthreads();                                      // S18
            if (tid < 4) {
                const int rg = r_wg + tid;
                float a = 0.0f;
#pragma unroll
                for (int o = 0; o < 8; ++o) a += sh_tmp[tid * 8 + o];
                float eps = -(sh_scal[2] + sh_scal[3]);
                gnxt[rg] = a + fbp[rg] + sh_k[rg] * eps;
            }
        }

        gbar(bar, wg, tid, tau + 1);
    }

    // ---- prediction chain: WG wg owns step pt = 64+wg ----
    {
        const float* Gf = Gb[0];
        const float* gf = gb[0];
        const int pt = NLB + wg;
        if (tid < NH) sh_z[tid] = Hw[pt * NH + tid];
        if (tid == 0) sh_scal[0] = Hb[pt];
        __syncthreads();
        for (int j = pt; j >= NLB; --j) {
            const float* Fj  = Fw + (size_t)j * NH * NH;
            const float* fbj = Fb + j * NH;
            {
                const int ib = tid >> 7, c = tid & 127;
                const float* base = Fj + (size_t)(ib * 16) * NH + c;
                float a = 0.0f;
#pragma unroll 8
                for (int i = 0; i < 16; ++i) a += sh_z[ib * 16 + i] * base[(size_t)i * NH];
                sh_part[tid] = a;
            }
            __syncthreads();
            if (tid < NH) {
                float a = 0.0f;
#pragma unroll
                for (int ib = 0; ib < 8; ++ib) a += sh_part[ib * NH + tid];
                sh_v[tid] = a;                                    // z' = F^T z
            } else if (tid < 192) {
                const int l = tid - 128;
                float a = sh_z[l] * fbj[l] + sh_z[l + 64] * fbj[l + 64];
                a = wave_reduce(a);
                if (l == 0) sh_scal[1] = a;                       // z.fb
            }
            __syncthreads();
            if (tid < NH) sh_z[tid] = sh_v[tid];
            if (tid == 0) sh_scal[0] += sh_scal[1];
            __syncthreads();
        }
        {
            const int mb = tid >> 6, c2 = tid & 63;
            const float* base = Gf + (size_t)(mb * 8) * 64 + c2;
            float a = 0.0f;
#pragma unroll
            for (int m = 0; m < 8; ++m) a += sh_z[mb * 8 + m] * base[(size_t)m * 64];
            sh_part[tid] = a;
        }
        __syncthreads();
        if (tid < 64) {
            float a = 0.0f;
#pragma unroll
            for (int mb = 0; mb < 16; ++mb) a += sh_part[mb * 64 + tid];
            Mrow[wg * 64 + tid] = a;
        } else if (tid < 128) {
            const int l = tid - 64;
            float a = sh_z[l] * gf[l] + sh_z[l + 64] * gf[l + 64];
            a = wave_reduce(a);
            if (l == 0) dvec[wg] = sh_scal[0] + a;
        }
    }
    gbar(bar, wg, tid, NLB + 2);

    // ---- batch pass: out[b,:] = M x[b,:] + d  (8192x64 @ 64x32) ----
    {
        for (int idx = tid; idx < NPW * 64; idx += NT) {
            int p = idx >> 6, t = idx & 63;
            Ml[p * 65 + t] = Mrow[p * 64 + t];
        }
        if (tid < NPW) dl[tid] = dvec[tid];
        __syncthreads();

        const int base_b = wg * 256;
        for (int chunk = 0; chunk < 2; ++chunk) {
            const int b0 = base_b + chunk * 128;
#pragma unroll
            for (int q = 0; q < 2; ++q) {
                int f4 = q * NT + tid;                 // 0..2047
                int rr = f4 >> 4, c4 = (f4 & 15) << 2;
                *(float4*)&sbuf[rr * 68 + c4] =
                    *(const float4*)&x[(size_t)(b0 + rr) * NLB + c4];
            }
            __syncthreads();
            const int rr = tid >> 3;                   // 0..127
            const int pg = tid & 7;
            const float* xr = &sbuf[rr * 68];
            float acc[4];
#pragma unroll
            for (int pi = 0; pi < 4; ++pi) acc[pi] = dl[pg * 4 + pi];
            for (int t = 0; t < NLB; ++t) {
                float xv = xr[t];
#pragma unroll
                for (int pi = 0; pi < 4; ++pi)
                    acc[pi] += xv * Ml[(pg * 4 + pi) * 65 + t];
            }
            *(float4*)&out[(size_t)(b0 + rr) * NPW + pg * 4] =
                make_float4(acc[0], acc[1], acc[2], acc[3]);
            __syncthreads();
        }
    }
}

extern "C" void kernel_launch(void* const* d_in, const int* in_sizes, int n_in,
                              void* d_out, int out_size, void* d_ws, size_t ws_size,
                              hipStream_t stream) {
    const float* x          = (const float*)d_in[0];
    const float* F_w        = (const float*)d_in[1];
    const float* F_b        = (const float*)d_in[2];
    const float* H_w        = (const float*)d_in[3];
    const float* H_b        = (const float*)d_in[4];
    const float* init_state = (const float*)d_in[5];
    const float* init_cov   = (const float*)d_in[6];
    const float* Qm         = (const float*)d_in[7];
    const float* Rm         = (const float*)d_in[8];

    kalman_fused<<<dim3(NWG), dim3(NT), 0, stream>>>(
        x, F_w, F_b, H_w, H_b, init_state, init_cov, Qm, Rm,
        (float*)d_ws, (float*)d_out);
}